// Round 12
// baseline (269.885 us; speedup 1.0000x reference)
//
#include <hip/hip_runtime.h>
#include <stdint.h>

typedef __bf16 bf16;
typedef bf16 bf16x4 __attribute__((ext_vector_type(4)));
typedef bf16 bf16x8 __attribute__((ext_vector_type(8)));
typedef float f32x4 __attribute__((ext_vector_type(4)));

// Inputs fp32, output fp32. Internal: bf16 MFMA, fp32 acc.
// Q is pre-scaled by 0.125*log2(e) in the QKV epilogue so attention softmax
// is exp2(s) with zero extra VALU per element.

// Async global->LDS, 16B/lane; LDS dest = wave-uniform base + lane*16 [m97].
__device__ __forceinline__ void gll16(const bf16* g, const bf16* l) {
  __builtin_amdgcn_global_load_lds(
      (__attribute__((address_space(1))) void*)(g),
      (__attribute__((address_space(3))) void*)(l),
      16, 0, 0);
}

// ---------------- LayerNorm: one block per row of 1024, fp32 in -> bf16 out ----------------
__global__ __launch_bounds__(256) void ln_kernel(
    const float* __restrict__ x, const float* __restrict__ gamma,
    const float* __restrict__ beta, bf16* __restrict__ xn)
{
  __shared__ float red[8];
  const long row = blockIdx.x;
  const int t = threadIdx.x;
  f32x4 f = *(const f32x4*)(x + row * 1024 + t * 4);
  float sum = f[0] + f[1] + f[2] + f[3];
  float sq  = f[0]*f[0] + f[1]*f[1] + f[2]*f[2] + f[3]*f[3];
#pragma unroll
  for (int sh = 1; sh < 64; sh <<= 1) {
    sum += __shfl_xor(sum, sh, 64);
    sq  += __shfl_xor(sq,  sh, 64);
  }
  const int wave = t >> 6, lane = t & 63;
  if (lane == 0) { red[wave] = sum; red[wave + 4] = sq; }
  __syncthreads();
  sum = red[0] + red[1] + red[2] + red[3];
  sq  = red[4] + red[5] + red[6] + red[7];
  const float mu  = sum * (1.0f / 1024.0f);
  const float var = sq * (1.0f / 1024.0f) - mu * mu;
  const float rs  = rsqrtf(var + 1e-5f);
  f32x4 g = *(const f32x4*)(gamma + t * 4);
  f32x4 bb = *(const f32x4*)(beta + t * 4);
  bf16x4 ov;
#pragma unroll
  for (int i = 0; i < 4; i++)
    ov[i] = (bf16)((f[i] - mu) * rs * g[i] + bb[i]);
  *(bf16x4*)(xn + row * 1024 + t * 4) = ov;
}

// ---------------- Weight transposes (both weights, one launch): out[c][r] = (bf16)in[r][c] ----------------
__global__ __launch_bounds__(256) void transpose2_kernel(
    const float* __restrict__ wqkv, bf16* __restrict__ wqkvT,
    const float* __restrict__ wout, bf16* __restrict__ woutT)
{
  __shared__ bf16 tile[32][33];
  const int bx = blockIdx.x;
  const float* in;
  bf16* out;
  int Cc, c0;
  if (bx < 96) { in = wqkv; out = wqkvT; Cc = 3072; c0 = bx * 32; }
  else         { in = wout; out = woutT; Cc = 1024; c0 = (bx - 96) * 32; }
  const int r0 = blockIdx.y * 32;
  const int tx = threadIdx.x & 31, ty = threadIdx.x >> 5;
#pragma unroll
  for (int i = 0; i < 32; i += 8)
    tile[ty + i][tx] = (bf16)in[(long)(r0 + ty + i) * Cc + c0 + tx];
  __syncthreads();
#pragma unroll
  for (int i = 0; i < 32; i += 8)
    out[(long)(c0 + ty + i) * 1024 + r0 + tx] = tile[tx][ty + i];
}

// ---------------- V transpose: vb[bh][l][64] -> vt[bh][64][l] (both sides coalesced) ----------------
// R12: the GEMM no longer scatter-transposes V (adjacent lanes were 4KB apart
// -> one 32B sector transaction per 2B store, ~8.4M of them = the hidden
// constant cost every R3-R11 GEMM variant shared). Proven 32x33 LDS-tile
// pattern; 32MB traffic ~= 6-8 us at HBM BW.
__global__ __launch_bounds__(256) void vtrans_kernel(
    const bf16* __restrict__ vb, bf16* __restrict__ vt)
{
  __shared__ bf16 tile[32][33];
  const int i = blockIdx.x;            // 0..8191
  const int bh = i >> 7;               // 64 bh
  const int r = i & 127;               // 64 l-tiles x 2 d-tiles
  const int l0 = (r & 63) * 32;
  const int d0 = (r >> 6) * 32;
  const long base = (long)bh * 131072; // 2048*64
  const int tx = threadIdx.x & 31, ty = threadIdx.x >> 5;
#pragma unroll
  for (int s = 0; s < 32; s += 8)
    tile[ty + s][tx] = vb[base + (long)(l0 + ty + s) * 64 + d0 + tx];
  __syncthreads();
#pragma unroll
  for (int s = 0; s < 32; s += 8)
    vt[base + (long)(d0 + ty + s) * 2048 + l0 + tx] = tile[tx][ty + s];
}

// ---------------- GEMM: C[m][n] = sum_k A[m][k] * BT[n][k] + bias[n] ----------------
// R11 body kept (2-buffer ping-pong, one barrier/step, (256,4), R5 swizzles:
// bank conflicts verified 0). R12 change: mode-1 epilogue is now FULLY
// COALESCED — q/k/v all stored [bh][l][64] (adjacent c16 lanes -> adjacent d,
// 32B contiguous segments); V transposed later by vtrans_kernel.
// mode 0: store C [M][N] fp32. mode 1: q scaled by 0.125*log2e; k, v plain.
__global__ __launch_bounds__(256, 4) void gemm_bt(
    const bf16* __restrict__ A, const bf16* __restrict__ BT,
    const float* __restrict__ bias, float* __restrict__ C,
    bf16* __restrict__ qb, bf16* __restrict__ kb, bf16* __restrict__ vb,
    int K, int N, int mode)
{
  __shared__ bf16 sA[2][128 * 32];
  __shared__ bf16 sB[2][128 * 32];
  const int t = threadIdx.x;
  const int lane = t & 63;
  const int wave = t >> 6;
  const int wave_u = __builtin_amdgcn_readfirstlane(wave);
  const int quad = lane >> 4;
  const int c16 = lane & 15;
  const int wm = (wave >> 1) * 64;
  const int wn = (wave & 1) * 64;
  const int m0 = blockIdx.x * 128;
  const int n0 = blockIdx.y * 128;

  f32x4 acc[4][4] = {};

  const int srow = t >> 2;                               // 0..63
  const int scol = (((t & 3) ^ ((t >> 3) & 3)) * 8);     // pre-swizzled source granule
  const bf16* gA = A + (long)(m0 + srow) * K + scol;
  const bf16* gB = BT + (long)(n0 + srow) * K + scol;
  const long rowskip = (long)64 * K;
  const int ksw = (quad ^ ((c16 >> 1) & 3)) * 8;         // swizzled read offset (elems)

  const int S = K >> 5;

  auto stage = [&](int b, int kk) {
    const bf16* lA = sA[0] + b * 4096 + wave_u * 512;
    const bf16* lB = sB[0] + b * 4096 + wave_u * 512;
    const int k0 = kk * 32;
    gll16(gA + k0, lA);
    gll16(gA + k0 + rowskip, lA + 2048);
    gll16(gB + k0, lB);
    gll16(gB + k0 + rowskip, lB + 2048);
  };

  // prologue: stage step 0 into buffer 0
  stage(0, 0);

  int cur = 0;
  for (int s = 0; s < S; s++) {
    __syncthreads();                 // stage(s) visible; prev reads of buf[cur^1] done
    if (s + 1 < S)
      stage(cur ^ 1, s + 1);         // in flight across this step's compute
    const bf16* cA = sA[0] + cur * 4096;
    const bf16* cB = sB[0] + cur * 4096;
    bf16x8 af[4], bfr[4];
#pragma unroll
    for (int i = 0; i < 4; i++)
      af[i] = *(const bf16x8*)(cA + (wm + i * 16 + c16) * 32 + ksw);
#pragma unroll
    for (int j = 0; j < 4; j++)
      bfr[j] = *(const bf16x8*)(cB + (wn + j * 16 + c16) * 32 + ksw);
#pragma unroll
    for (int i = 0; i < 4; i++)
#pragma unroll
      for (int j = 0; j < 4; j++)
        acc[i][j] = __builtin_amdgcn_mfma_f32_16x16x32_bf16(af[i], bfr[j], acc[i][j], 0, 0, 0);
    cur ^= 1;
  }

  // C/D layout: col = lane&15, row = quad*4 + reg   [verified m89/m91]
#pragma unroll
  for (int i = 0; i < 4; i++) {
    const int mbase = m0 + wm + i * 16 + quad * 4;
#pragma unroll
    for (int j = 0; j < 4; j++) {
      const int n = n0 + wn + j * 16 + c16;
      const float bv = bias[n];
      if (mode == 0) {
#pragma unroll
        for (int r = 0; r < 4; r++)
          C[(long)(mbase + r) * N + n] = acc[i][j][r] + bv;
      } else {
        const int part = n >> 10;       // 0=Q 1=K 2=V
        const int inner = n & 1023;
        const int h = inner >> 6, d = inner & 63;
        bf16* dst = (part == 0) ? qb : (part == 1) ? kb : vb;
        const float scl = (part == 0) ? 0.18033688f : 1.0f;   // 0.125*log2e for Q
#pragma unroll
        for (int r = 0; r < 4; r++) {
          const int m = mbase + r;
          const int b = m >> 11, l = m & 2047;
          const long bh = (long)((b << 4) | h);
          dst[(bh * 2048 + l) * 64 + d] = (bf16)((acc[i][j][r] + bv) * scl);
        }
      }
    }
  }
}

// ---------------- Flash attention: swapped QK^T, P in registers, 64 q-rows/wave ----------------
// (unchanged from R6; see R6 notes)
__global__ __launch_bounds__(256, 2) void attn_kernel(
    const bf16* __restrict__ q, const bf16* __restrict__ k,
    const bf16* __restrict__ vt, bf16* __restrict__ att)
{
  __shared__ bf16 sK[128 * 68];
  __shared__ bf16 sVt[64 * 132];

  const int i = blockIdx.x;                 // 0..511
  const int xcd = i & 7;
  const int wi = i >> 3;                    // 0..63
  const int qt = wi & 7;
  const int bh = xcd * 8 + (wi >> 3);
  const int b = bh >> 4, h = bh & 15;
  const int q0 = qt * 256;
  const int t = threadIdx.x;
  const int wave = t >> 6, lane = t & 63;
  const int quad = lane >> 4, c16 = lane & 15;

  const bf16* qp = q + (long)bh * (2048 * 64);
  const bf16* kp = k + (long)bh * (2048 * 64);
  const bf16* vp = vt + (long)bh * (64 * 2048);

  bf16x8 aq[4][2];
#pragma unroll
  for (int m = 0; m < 4; m++) {
    const bf16* qrow = qp + (long)(q0 + wave * 64 + m * 16 + c16) * 64 + quad * 8;
    aq[m][0] = *(const bf16x8*)(qrow);
    aq[m][1] = *(const bf16x8*)(qrow + 32);
  }

  f32x4 o_acc[4][4] = {};
  f32x4 o_sum[4] = {};
  bf16x8 vones;
#pragma unroll
  for (int z = 0; z < 8; z++) vones[z] = (bf16)1.0f;

  const int kr = t >> 3;
  const int kd = (t & 7) * 8;
  const int vr = t >> 4;
  const int vc = t & 15;
  const int vl = vc * 8;
  const int vD0 = (vc >> 2) * 32 + (vc & 1) * 16 + ((vc >> 1) & 1) * 4;

  bf16x8 kreg[4], vreg[4];
#pragma unroll
  for (int it = 0; it < 4; it++) {
    kreg[it] = *(const bf16x8*)(kp + (long)(it * 32 + kr) * 64 + kd);
    vreg[it] = *(const bf16x8*)(vp + (long)(it * 16 + vr) * 2048 + vl);
  }

  for (int kt = 0; kt < 16; kt++) {
    __syncthreads();
#pragma unroll
    for (int it = 0; it < 4; it++)
      *(bf16x8*)&sK[(it * 32 + kr) * 68 + kd] = kreg[it];
#pragma unroll
    for (int it = 0; it < 4; it++) {
      const bf16x8 v = vreg[it];
      const bf16x4 lo = __builtin_shufflevector(v, v, 0, 1, 2, 3);
      const bf16x4 hi = __builtin_shufflevector(v, v, 4, 5, 6, 7);
      bf16* d = &sVt[(it * 16 + vr) * 132 + vD0];
      *(bf16x4*)(d)     = lo;
      *(bf16x4*)(d + 8) = hi;
    }
    __syncthreads();

    const int kvn = ((kt + 1) & 15) * 128;

#pragma unroll
    for (int ks = 0; ks < 4; ks++) {
      bf16x8 ap[4];
#pragma unroll
      for (int e = 0; e < 2; e++) {
        const int jb = ks * 2 + e;
        const bf16x8 bk0 = *(const bf16x8*)&sK[(jb * 16 + c16) * 68 + quad * 8];
        const bf16x8 bk1 = *(const bf16x8*)&sK[(jb * 16 + c16) * 68 + 32 + quad * 8];
#pragma unroll
        for (int m = 0; m < 4; m++) {
          f32x4 z = {};
          z = __builtin_amdgcn_mfma_f32_16x16x32_bf16(bk0, aq[m][0], z, 0, 0, 0);
          z = __builtin_amdgcn_mfma_f32_16x16x32_bf16(bk1, aq[m][1], z, 0, 0, 0);
#pragma unroll
          for (int r = 0; r < 4; r++)
            ap[m][e * 4 + r] = (bf16)__builtin_amdgcn_exp2f(z[r]);
        }
      }
      if (ks == 1) {
#pragma unroll
        for (int it = 0; it < 4; it++)
          kreg[it] = *(const bf16x8*)(kp + (long)(kvn + it * 32 + kr) * 64 + kd);
      }
      if (ks == 2) {
#pragma unroll
        for (int it = 0; it < 4; it++)
          vreg[it] = *(const bf16x8*)(vp + (long)(it * 16 + vr) * 2048 + kvn + vl);
      }
#pragma unroll
      for (int m = 0; m < 4; m++)
        o_sum[m] = __builtin_amdgcn_mfma_f32_16x16x32_bf16(ap[m], vones, o_sum[m], 0, 0, 0);
#pragma unroll
      for (int jd = 0; jd < 4; jd++) {
        const bf16x8 bv = *(const bf16x8*)&sVt[(jd * 16 + c16) * 132 + ks * 32 + quad * 8];
#pragma unroll
        for (int m = 0; m < 4; m++)
          o_acc[m][jd] = __builtin_amdgcn_mfma_f32_16x16x32_bf16(ap[m], bv, o_acc[m][jd], 0, 0, 0);
      }
    }
  }

#pragma unroll
  for (int m = 0; m < 4; m++) {
#pragma unroll
    for (int r = 0; r < 4; r++) {
      const float inv = 1.0f / o_sum[m][r];
      const long rowbase = ((long)b * 2048 + q0 + wave * 64 + m * 16 + quad * 4 + r) * 1024 + h * 64;
#pragma unroll
      for (int jd = 0; jd < 4; jd++)
        att[rowbase + jd * 16 + c16] = (bf16)(o_acc[m][jd][r] * inv);
    }
  }
}

// ---------------- launcher ----------------
extern "C" void kernel_launch(void* const* d_in, const int* in_sizes, int n_in,
                              void* d_out, int out_size, void* d_ws, size_t ws_size,
                              hipStream_t stream) {
  (void)in_sizes; (void)n_in; (void)out_size; (void)ws_size;
  const float* x     = (const float*)d_in[0];
  const float* w_qkv = (const float*)d_in[1];
  const float* b_qkv = (const float*)d_in[2];
  const float* w_out = (const float*)d_in[3];
  const float* b_out = (const float*)d_in[4];
  const float* gamma = (const float*)d_in[5];
  const float* beta  = (const float*)d_in[6];
  float* out = (float*)d_out;
  bf16* ws  = (bf16*)d_ws;

  // ws layout (bf16 elems), total 37.75M elems = 75.5 MB
  bf16* xn    = ws;                    // 8192*1024 (reused as att buffer)
  bf16* wqkvT = ws + 8388608;          // 3072*1024
  bf16* woutT = wqkvT + 3145728;       // 1024*1024
  bf16* qbuf  = woutT + 1048576;       // 8192*1024
  bf16* kbuf  = qbuf + 8388608;        // 8192*1024
  bf16* vtbuf = kbuf + 8388608;        // 8192*1024
  bf16* att   = xn;                    // alias: xn dead after QKV GEMM
  // vb (untransposed V) aliases d_out: 16.8MB < 33.5MB, dead until out-proj,
  // which runs after vtrans+attn have consumed it.
  bf16* vb    = (bf16*)d_out;

  transpose2_kernel<<<dim3(128, 32), 256, 0, stream>>>(w_qkv, wqkvT, w_out, woutT);
  ln_kernel<<<dim3(8192), 256, 0, stream>>>(x, gamma, beta, xn);
  gemm_bt<<<dim3(8192 / 128, 3072 / 128), 256, 0, stream>>>(
      xn, wqkvT, b_qkv, (float*)nullptr, qbuf, kbuf, vb, 1024, 3072, 1);
  vtrans_kernel<<<dim3(8192), 256, 0, stream>>>(vb, vtbuf);
  attn_kernel<<<dim3(512), 256, 0, stream>>>(qbuf, kbuf, vtbuf, att);
  gemm_bt<<<dim3(8192 / 128, 1024 / 128), 256, 0, stream>>>(
      att, woutT, b_out, out, (bf16*)nullptr, (bf16*)nullptr, (bf16*)nullptr, 1024, 1024, 0);
}

// Round 13
// 254.359 us; speedup vs baseline: 1.0610x; 1.0610x over previous
//
#include <hip/hip_runtime.h>
#include <stdint.h>

typedef __bf16 bf16;
typedef bf16 bf16x4 __attribute__((ext_vector_type(4)));
typedef bf16 bf16x8 __attribute__((ext_vector_type(8)));
typedef float f32x4 __attribute__((ext_vector_type(4)));

// Inputs fp32, output fp32. Internal: bf16 MFMA, fp32 acc.
// Q is pre-scaled by 0.125*log2(e) in the QKV epilogue so attention softmax
// is exp2(s) with zero extra VALU per element.

// Async global->LDS, 16B/lane; LDS dest = wave-uniform base + lane*16 [m97].
__device__ __forceinline__ void gll16(const bf16* g, const bf16* l) {
  __builtin_amdgcn_global_load_lds(
      (__attribute__((address_space(1))) void*)(g),
      (__attribute__((address_space(3))) void*)(l),
      16, 0, 0);
}

// ---------------- Prep: weight transposes + LayerNorm in ONE launch ----------------
// R13: 6 dispatches -> 4. Launch-boundary cost ~10us each [rocprof.md] was
// ~25% of wall time; fusing independent preprocessing saves one boundary.
// bid < 4096: 32x32 transpose tiles (bx<96: w_qkv 1024x3072; else w_out
// 1024x1024). bid >= 4096: LN row (bid-4096) of x.
__global__ __launch_bounds__(256) void prep_kernel(
    const float* __restrict__ wqkv, bf16* __restrict__ wqkvT,
    const float* __restrict__ wout, bf16* __restrict__ woutT,
    const float* __restrict__ x, const float* __restrict__ gamma,
    const float* __restrict__ beta, bf16* __restrict__ xn)
{
  __shared__ bf16 tile[32][33];
  __shared__ float red[8];
  const int bid = blockIdx.x;
  const int t = threadIdx.x;
  if (bid < 4096) {
    const int bx = bid & 127, by = bid >> 7;
    const float* in;
    bf16* out;
    int Cc, c0;
    if (bx < 96) { in = wqkv; out = wqkvT; Cc = 3072; c0 = bx * 32; }
    else         { in = wout; out = woutT; Cc = 1024; c0 = (bx - 96) * 32; }
    const int r0 = by * 32;
    const int tx = t & 31, ty = t >> 5;
#pragma unroll
    for (int i = 0; i < 32; i += 8)
      tile[ty + i][tx] = (bf16)in[(long)(r0 + ty + i) * Cc + c0 + tx];
    __syncthreads();
#pragma unroll
    for (int i = 0; i < 32; i += 8)
      out[(long)(c0 + ty + i) * 1024 + r0 + tx] = tile[tx][ty + i];
  } else {
    const long row = bid - 4096;
    f32x4 f = *(const f32x4*)(x + row * 1024 + t * 4);
    float sum = f[0] + f[1] + f[2] + f[3];
    float sq  = f[0]*f[0] + f[1]*f[1] + f[2]*f[2] + f[3]*f[3];
#pragma unroll
    for (int sh = 1; sh < 64; sh <<= 1) {
      sum += __shfl_xor(sum, sh, 64);
      sq  += __shfl_xor(sq,  sh, 64);
    }
    const int wave = t >> 6, lane = t & 63;
    if (lane == 0) { red[wave] = sum; red[wave + 4] = sq; }
    __syncthreads();
    sum = red[0] + red[1] + red[2] + red[3];
    sq  = red[4] + red[5] + red[6] + red[7];
    const float mu  = sum * (1.0f / 1024.0f);
    const float var = sq * (1.0f / 1024.0f) - mu * mu;
    const float rs  = rsqrtf(var + 1e-5f);
    f32x4 g = *(const f32x4*)(gamma + t * 4);
    f32x4 bb = *(const f32x4*)(beta + t * 4);
    bf16x4 ov;
#pragma unroll
    for (int i = 0; i < 4; i++)
      ov[i] = (bf16)((f[i] - mu) * rs * g[i] + bb[i]);
    *(bf16x4*)(xn + row * 1024 + t * 4) = ov;
  }
}

// ---------------- GEMM: C[m][n] = sum_k A[m][k] * BT[n][k] + bias[n] ----------------
// R11 body (2-buffer ping-pong, one barrier/step, (256,4), R5 swizzles:
// bank conflicts verified 0). R12 epilogue: mode-1 fully coalesced — q/k/v
// all stored [bh][l][64]; V transposed inside attn's staging (R13).
// mode 0: store C [M][N] fp32. mode 1: q scaled by 0.125*log2e; k, v plain.
__global__ __launch_bounds__(256, 4) void gemm_bt(
    const bf16* __restrict__ A, const bf16* __restrict__ BT,
    const float* __restrict__ bias, float* __restrict__ C,
    bf16* __restrict__ qb, bf16* __restrict__ kb, bf16* __restrict__ vb,
    int K, int N, int mode)
{
  __shared__ bf16 sA[2][128 * 32];
  __shared__ bf16 sB[2][128 * 32];
  const int t = threadIdx.x;
  const int lane = t & 63;
  const int wave = t >> 6;
  const int wave_u = __builtin_amdgcn_readfirstlane(wave);
  const int quad = lane >> 4;
  const int c16 = lane & 15;
  const int wm = (wave >> 1) * 64;
  const int wn = (wave & 1) * 64;
  const int m0 = blockIdx.x * 128;
  const int n0 = blockIdx.y * 128;

  f32x4 acc[4][4] = {};

  const int srow = t >> 2;                               // 0..63
  const int scol = (((t & 3) ^ ((t >> 3) & 3)) * 8);     // pre-swizzled source granule
  const bf16* gA = A + (long)(m0 + srow) * K + scol;
  const bf16* gB = BT + (long)(n0 + srow) * K + scol;
  const long rowskip = (long)64 * K;
  const int ksw = (quad ^ ((c16 >> 1) & 3)) * 8;         // swizzled read offset (elems)

  const int S = K >> 5;

  auto stage = [&](int b, int kk) {
    const bf16* lA = sA[0] + b * 4096 + wave_u * 512;
    const bf16* lB = sB[0] + b * 4096 + wave_u * 512;
    const int k0 = kk * 32;
    gll16(gA + k0, lA);
    gll16(gA + k0 + rowskip, lA + 2048);
    gll16(gB + k0, lB);
    gll16(gB + k0 + rowskip, lB + 2048);
  };

  // prologue: stage step 0 into buffer 0
  stage(0, 0);

  int cur = 0;
  for (int s = 0; s < S; s++) {
    __syncthreads();                 // stage(s) visible; prev reads of buf[cur^1] done
    if (s + 1 < S)
      stage(cur ^ 1, s + 1);         // in flight across this step's compute
    const bf16* cA = sA[0] + cur * 4096;
    const bf16* cB = sB[0] + cur * 4096;
    bf16x8 af[4], bfr[4];
#pragma unroll
    for (int i = 0; i < 4; i++)
      af[i] = *(const bf16x8*)(cA + (wm + i * 16 + c16) * 32 + ksw);
#pragma unroll
    for (int j = 0; j < 4; j++)
      bfr[j] = *(const bf16x8*)(cB + (wn + j * 16 + c16) * 32 + ksw);
#pragma unroll
    for (int i = 0; i < 4; i++)
#pragma unroll
      for (int j = 0; j < 4; j++)
        acc[i][j] = __builtin_amdgcn_mfma_f32_16x16x32_bf16(af[i], bfr[j], acc[i][j], 0, 0, 0);
    cur ^= 1;
  }

  // C/D layout: col = lane&15, row = quad*4 + reg   [verified m89/m91]
#pragma unroll
  for (int i = 0; i < 4; i++) {
    const int mbase = m0 + wm + i * 16 + quad * 4;
#pragma unroll
    for (int j = 0; j < 4; j++) {
      const int n = n0 + wn + j * 16 + c16;
      const float bv = bias[n];
      if (mode == 0) {
#pragma unroll
        for (int r = 0; r < 4; r++)
          C[(long)(mbase + r) * N + n] = acc[i][j][r] + bv;
      } else {
        const int part = n >> 10;       // 0=Q 1=K 2=V
        const int inner = n & 1023;
        const int h = inner >> 6, d = inner & 63;
        bf16* dst = (part == 0) ? qb : (part == 1) ? kb : vb;
        const float scl = (part == 0) ? 0.18033688f : 1.0f;   // 0.125*log2e for Q
#pragma unroll
        for (int r = 0; r < 4; r++) {
          const int m = mbase + r;
          const int b = m >> 11, l = m & 2047;
          const long bh = (long)((b << 4) | h);
          dst[(bh * 2048 + l) * 64 + d] = (bf16)((acc[i][j][r] + bv) * scl);
        }
      }
    }
  }
}

// ---------------- Flash attention: swapped QK^T, P in registers, 64 q-rows/wave ----------------
// R13 changes vs R12:
//  * V read DIRECTLY from vb[bh][l][64] (vtrans kernel deleted): staging
//    thread t owns tile row lr=t>>1, d-half dh=(t&1)*32; reads 4x b128
//    coalesced, writes 32 compile-time-indexed ds_write_b16 performing the
//    transpose + sigma-permutation (verified element-wise vs the R3 vD0
//    path). ~4-way write conflicts accepted (writes are ~1% of wave cycles).
//  * T5 setprio(1) around the pure-MFMA PV cluster [m191: attn +4-7%].
// Carried: swapped QK^T (P lane-local, no LDS round-trip), kv-sigma
// permutation on both operands, ones-MFMA row sums, XCD-affine bh placement,
// K/V register-prefetch one tile ahead issued mid-compute, 2 barriers/iter.
__global__ __launch_bounds__(256, 2) void attn_kernel(
    const bf16* __restrict__ q, const bf16* __restrict__ k,
    const bf16* __restrict__ vb, bf16* __restrict__ att)
{
  __shared__ bf16 sK[128 * 68];      // [kv][d], stride 68 (34 words, mod32=2)
  __shared__ bf16 sVt[64 * 132];     // [d][kv-permuted], stride 132

  const int i = blockIdx.x;                 // 0..511
  const int xcd = i & 7;
  const int wi = i >> 3;                    // 0..63
  const int qt = wi & 7;
  const int bh = xcd * 8 + (wi >> 3);
  const int b = bh >> 4, h = bh & 15;
  const int q0 = qt * 256;
  const int t = threadIdx.x;
  const int wave = t >> 6, lane = t & 63;
  const int quad = lane >> 4, c16 = lane & 15;

  const bf16* qp = q + (long)bh * (2048 * 64);
  const bf16* kp = k + (long)bh * (2048 * 64);
  const bf16* vp = vb + (long)bh * (2048 * 64);   // [l][d] layout

  bf16x8 aq[4][2];
#pragma unroll
  for (int m = 0; m < 4; m++) {
    const bf16* qrow = qp + (long)(q0 + wave * 64 + m * 16 + c16) * 64 + quad * 8;
    aq[m][0] = *(const bf16x8*)(qrow);
    aq[m][1] = *(const bf16x8*)(qrow + 32);
  }

  f32x4 o_acc[4][4] = {};
  f32x4 o_sum[4] = {};
  bf16x8 vones;
#pragma unroll
  for (int z = 0; z < 8; z++) vones[z] = (bf16)1.0f;

  // K staging indices
  const int kr = t >> 3;             // K row within 32-row group
  const int kd = (t & 7) * 8;
  // V staging indices (transpose-on-LDS-write)
  const int lr = t >> 1;             // tile row l (0..127)
  const int dh = (t & 1) * 32;       // d half base
  const int l32 = lr & 31;
  const int pcol = (lr >> 5) * 32 + ((l32 >> 2) & 3) * 8 + (l32 >> 4) * 4 + (l32 & 3);

  bf16x8 kreg[4], vreg[4];
#pragma unroll
  for (int it = 0; it < 4; it++)
    kreg[it] = *(const bf16x8*)(kp + (long)(it * 32 + kr) * 64 + kd);
#pragma unroll
  for (int c = 0; c < 4; c++)
    vreg[c] = *(const bf16x8*)(vp + (long)lr * 64 + dh + c * 8);

  for (int kt = 0; kt < 16; kt++) {
    __syncthreads();   // b1: prev iter's LDS reads done
#pragma unroll
    for (int it = 0; it < 4; it++)
      *(bf16x8*)&sK[(it * 32 + kr) * 68 + kd] = kreg[it];
    // V transpose + sigma-permute into sVt (32 scalar b16, indices compile-time)
#pragma unroll
    for (int c = 0; c < 4; c++)
#pragma unroll
      for (int u = 0; u < 8; u++)
        sVt[(dh + c * 8 + u) * 132 + pcol] = vreg[c][u];
    __syncthreads();   // b2: tiles visible

    const int kvn = ((kt + 1) & 15) * 128;

#pragma unroll
    for (int ks = 0; ks < 4; ks++) {
      bf16x8 ap[4];
      // QK^T (swapped) + exp2 + lane-local pack for this 32-kv chunk
#pragma unroll
      for (int e = 0; e < 2; e++) {
        const int jb = ks * 2 + e;
        const bf16x8 bk0 = *(const bf16x8*)&sK[(jb * 16 + c16) * 68 + quad * 8];
        const bf16x8 bk1 = *(const bf16x8*)&sK[(jb * 16 + c16) * 68 + 32 + quad * 8];
#pragma unroll
        for (int m = 0; m < 4; m++) {
          f32x4 z = {};
          z = __builtin_amdgcn_mfma_f32_16x16x32_bf16(bk0, aq[m][0], z, 0, 0, 0);
          z = __builtin_amdgcn_mfma_f32_16x16x32_bf16(bk1, aq[m][1], z, 0, 0, 0);
#pragma unroll
          for (int r = 0; r < 4; r++)
            ap[m][e * 4 + r] = (bf16)__builtin_amdgcn_exp2f(z[r]);   // slot sigma(kv)
        }
      }
      // mid-compute prefetch of next tile
      if (ks == 1) {
#pragma unroll
        for (int it = 0; it < 4; it++)
          kreg[it] = *(const bf16x8*)(kp + (long)(kvn + it * 32 + kr) * 64 + kd);
      }
      if (ks == 2) {
#pragma unroll
        for (int c = 0; c < 4; c++)
          vreg[c] = *(const bf16x8*)(vp + (long)(kvn + lr) * 64 + dh + c * 8);
      }
      // pure-MFMA cluster: row-sums (B=ones) + O += P @ V   [T5]
      __builtin_amdgcn_s_setprio(1);
#pragma unroll
      for (int m = 0; m < 4; m++)
        o_sum[m] = __builtin_amdgcn_mfma_f32_16x16x32_bf16(ap[m], vones, o_sum[m], 0, 0, 0);
#pragma unroll
      for (int jd = 0; jd < 4; jd++) {
        const bf16x8 bv = *(const bf16x8*)&sVt[(jd * 16 + c16) * 132 + ks * 32 + quad * 8];
#pragma unroll
        for (int m = 0; m < 4; m++)
          o_acc[m][jd] = __builtin_amdgcn_mfma_f32_16x16x32_bf16(ap[m], bv, o_acc[m][jd], 0, 0, 0);
      }
      __builtin_amdgcn_s_setprio(0);
    }
  }

  // epilogue: o_acc/o_sum D-layout row = q_local = quad*4+r, col = c16.
#pragma unroll
  for (int m = 0; m < 4; m++) {
#pragma unroll
    for (int r = 0; r < 4; r++) {
      const float inv = 1.0f / o_sum[m][r];
      const long rowbase = ((long)b * 2048 + q0 + wave * 64 + m * 16 + quad * 4 + r) * 1024 + h * 64;
#pragma unroll
      for (int jd = 0; jd < 4; jd++)
        att[rowbase + jd * 16 + c16] = (bf16)(o_acc[m][jd][r] * inv);
    }
  }
}

// ---------------- launcher ----------------
extern "C" void kernel_launch(void* const* d_in, const int* in_sizes, int n_in,
                              void* d_out, int out_size, void* d_ws, size_t ws_size,
                              hipStream_t stream) {
  (void)in_sizes; (void)n_in; (void)out_size; (void)ws_size;
  const float* x     = (const float*)d_in[0];
  const float* w_qkv = (const float*)d_in[1];
  const float* b_qkv = (const float*)d_in[2];
  const float* w_out = (const float*)d_in[3];
  const float* b_out = (const float*)d_in[4];
  const float* gamma = (const float*)d_in[5];
  const float* beta  = (const float*)d_in[6];
  float* out = (float*)d_out;
  bf16* ws  = (bf16*)d_ws;

  // ws layout (bf16 elems)
  bf16* xn    = ws;                    // 8192*1024 (reused as att buffer)
  bf16* wqkvT = ws + 8388608;          // 3072*1024
  bf16* woutT = wqkvT + 3145728;       // 1024*1024
  bf16* qbuf  = woutT + 1048576;       // 8192*1024
  bf16* kbuf  = qbuf + 8388608;        // 8192*1024
  bf16* att   = xn;                    // alias: xn dead after QKV GEMM
  // vb (untransposed V, [bh][l][64]) aliases d_out: 16.8MB < 33.5MB; consumed
  // by attn before the out-projection overwrites d_out (stream-ordered).
  bf16* vb    = (bf16*)d_out;

  prep_kernel<<<dim3(12288), 256, 0, stream>>>(w_qkv, wqkvT, w_out, woutT,
                                               x, gamma, beta, xn);
  gemm_bt<<<dim3(8192 / 128, 3072 / 128), 256, 0, stream>>>(
      xn, wqkvT, b_qkv, (float*)nullptr, qbuf, kbuf, vb, 1024, 3072, 1);
  attn_kernel<<<dim3(512), 256, 0, stream>>>(qbuf, kbuf, vb, att);
  gemm_bt<<<dim3(8192 / 128, 1024 / 128), 256, 0, stream>>>(
      att, woutT, b_out, out, (bf16*)nullptr, (bf16*)nullptr, (bf16*)nullptr, 1024, 1024, 0);
}